// Round 5
// baseline (614.398 us; speedup 1.0000x reference)
//
#include <hip/hip_runtime.h>
#include <hip/hip_bf16.h>

#define N_NODES 100000
#define E_NUM   1600000
#define IN_DIM  128
#define HID     64
#define NCLS    40
#define NBUCK   782      // ceil(N_NODES/128); bucket b owns nodes [b*128, b*128+128)
#define TILE_E  8192
#define NTILE   196      // ceil(E_NUM / TILE_E)

// ---------------- K1: H = relu(x @ W_in + b_in) ----------------------------
// W held in registers (4 chunks of 32 rows), sx read as broadcast float4.
__global__ __launch_bounds__(256) void k_in_gemm(
    const float* __restrict__ x, const float* __restrict__ W,
    const float* __restrict__ b, float* __restrict__ H)
{
    __shared__ float sx[16][IN_DIM];     // 8 KB
    const int t = threadIdx.x;
    const int lane = t & 63;
    const int w    = t >> 6;
    const int row0 = blockIdx.x * 16;    // N_NODES = 16 * 6250
    const float4* xsrc = (const float4*)(x + (size_t)row0 * IN_DIM);
    for (int i = t; i < 16 * IN_DIM / 4; i += 256) ((float4*)sx)[i] = xsrc[i];
    __syncthreads();

    const float bias = b[lane];
    float a0 = bias, a1 = bias, a2 = bias, a3 = bias;
    #pragma unroll 1
    for (int c = 0; c < 4; ++c) {        // 32-k chunks keep VGPR ~80
        float wreg[32];
        #pragma unroll
        for (int k = 0; k < 32; ++k) wreg[k] = W[(size_t)(c * 32 + k) * HID + lane];
        #pragma unroll
        for (int kk = 0; kk < 8; ++kk) {
            const int k0 = c * 32 + kk * 4;
            const float4 r0 = *(const float4*)&sx[w     ][k0];
            const float4 r1 = *(const float4*)&sx[w +  4][k0];
            const float4 r2 = *(const float4*)&sx[w +  8][k0];
            const float4 r3 = *(const float4*)&sx[w + 12][k0];
            const float w0 = wreg[kk*4], w1 = wreg[kk*4+1], w2 = wreg[kk*4+2], w3 = wreg[kk*4+3];
            a0 += r0.x*w0 + r0.y*w1 + r0.z*w2 + r0.w*w3;
            a1 += r1.x*w0 + r1.y*w1 + r1.z*w2 + r1.w*w3;
            a2 += r2.x*w0 + r2.y*w1 + r2.z*w2 + r2.w*w3;
            a3 += r3.x*w0 + r3.y*w1 + r3.z*w2 + r3.w*w3;
        }
    }
    const size_t base = (size_t)row0 * HID + lane;
    H[base +  w       * HID] = fmaxf(a0, 0.f);
    H[base + (w +  4) * HID] = fmaxf(a1, 0.f);
    H[base + (w +  8) * HID] = fmaxf(a2, 0.f);
    H[base + (w + 12) * HID] = fmaxf(a3, 0.f);
}

// ---------------- bucket partition + in-bucket CSR build -------------------
__global__ void k_zero_hist(int* __restrict__ h) {
    int i = blockIdx.x * 256 + threadIdx.x;
    if (i < NBUCK) h[i] = 0;
}

__global__ __launch_bounds__(256) void k_hist(
    const int* __restrict__ ei, int* __restrict__ hist)
{
    __shared__ int lh[NBUCK];
    const int t = threadIdx.x;
    for (int i = t; i < NBUCK; i += 256) lh[i] = 0;
    __syncthreads();
    const int e0 = blockIdx.x * TILE_E;
    for (int k = 0; k < TILE_E; k += 256) {
        int e = e0 + k + t;
        if (e < E_NUM) atomicAdd(&lh[ei[E_NUM + e] >> 7], 1);
    }
    __syncthreads();
    for (int i = t; i < NBUCK; i += 256) if (lh[i]) atomicAdd(&hist[i], lh[i]);
}

__global__ __launch_bounds__(1024) void k_scan(
    const int* __restrict__ hist, int* __restrict__ base, int* __restrict__ cursor)
{
    __shared__ int s[1024];
    const int t = threadIdx.x;
    const int v = (t < NBUCK) ? hist[t] : 0;
    s[t] = v; __syncthreads();
    for (int off = 1; off < 1024; off <<= 1) {
        int a = (t >= off) ? s[t - off] : 0;
        __syncthreads(); s[t] += a; __syncthreads();
    }
    if (t < NBUCK) { int ex = s[t] - v; base[t] = ex; cursor[t] = ex; }
    if (t == NBUCK) base[t] = E_NUM;
}

// tile-private chunk reservation -> block-exclusive contiguous writes
__global__ __launch_bounds__(256) void k_part(
    const int* __restrict__ ei, int* __restrict__ cursor, int* __restrict__ pairs)
{
    __shared__ int lh[NBUCK];
    __shared__ int lbase[NBUCK];
    __shared__ int lcnt[NBUCK];
    const int t = threadIdx.x;
    for (int i = t; i < NBUCK; i += 256) { lh[i] = 0; lcnt[i] = 0; }
    __syncthreads();
    const int e0 = blockIdx.x * TILE_E;
    for (int k = 0; k < TILE_E; k += 256) {
        int e = e0 + k + t;
        if (e < E_NUM) atomicAdd(&lh[ei[E_NUM + e] >> 7], 1);
    }
    __syncthreads();
    for (int i = t; i < NBUCK; i += 256)
        lbase[i] = lh[i] ? atomicAdd(&cursor[i], lh[i]) : 0;
    __syncthreads();
    for (int k = 0; k < TILE_E; k += 256) {
        int e = e0 + k + t;
        if (e < E_NUM) {
            int src = ei[e];
            int dst = ei[E_NUM + e];
            int b   = dst >> 7;
            int r   = atomicAdd(&lcnt[b], 1);
            pairs[lbase[b] + r] = (src << 7) | (dst & 127);  // src < 2^17, fits
        }
    }
}

// one block per bucket: exact per-node CSR, writes stay in block-owned region
__global__ __launch_bounds__(256) void k_bsort(
    const int* __restrict__ base, const int* __restrict__ pairs,
    int* __restrict__ srcs, int* __restrict__ row_start)
{
    __shared__ int cnt[128];
    __shared__ int sc[128];
    __shared__ int cur[128];
    const int t = threadIdx.x;
    const int b = blockIdx.x;
    const int beg = base[b], end = base[b + 1];
    if (t < 128) cnt[t] = 0;
    __syncthreads();
    for (int i = beg + t; i < end; i += 256)
        atomicAdd(&cnt[pairs[i] & 127], 1);
    __syncthreads();
    if (t < 128) sc[t] = cnt[t];
    __syncthreads();
    for (int off = 1; off < 128; off <<= 1) {
        int a = (t < 128 && t >= off) ? sc[t - off] : 0;
        __syncthreads();
        if (t < 128) sc[t] += a;
        __syncthreads();
    }
    const int node0 = b << 7;
    if (t < 128) {
        int ex = sc[t] - cnt[t];      // exclusive prefix within bucket
        cur[t] = ex;
        if (node0 + t < N_NODES) row_start[node0 + t] = beg + ex;
    }
    if (b == 0 && t == 0) row_start[N_NODES] = E_NUM;
    __syncthreads();
    for (int i = beg + t; i < end; i += 256) {
        int p = pairs[i];
        int r = atomicAdd(&cur[p & 127], 1);
        srcs[beg + r] = p >> 7;
    }
}

// ------- fused: U = H[n] + sum H[src]  then  Hout = relu(U @ W + b) --------
// GEMM tail: W in registers (2 chunks of 32), su read as broadcast float4.
__global__ __launch_bounds__(256) void k_gather_gemm(
    const int* __restrict__ row_start, const int* __restrict__ srcs,
    const float* __restrict__ Hin, const float* __restrict__ Wl,
    const float* __restrict__ bl, float* __restrict__ Hout)
{
    __shared__ float su[16][HID];     // 4 KB
    const int t = threadIdx.x;
    const int lane = t & 63;
    const int w    = t >> 6;
    const int row0 = blockIdx.x * 16;

    for (int q = 0; q < 4; ++q) {
        const int n = row0 + (w << 2) + q;
        const int beg = row_start[n];
        const int end = row_start[n + 1];
        float u = Hin[(size_t)n * HID + lane];
        int i = beg;
        for (; i + 7 < end; i += 8) {
            const int s0 = srcs[i    ], s1 = srcs[i + 1], s2 = srcs[i + 2], s3 = srcs[i + 3];
            const int s4 = srcs[i + 4], s5 = srcs[i + 5], s6 = srcs[i + 6], s7 = srcs[i + 7];
            const float v0 = Hin[(size_t)s0 * HID + lane];
            const float v1 = Hin[(size_t)s1 * HID + lane];
            const float v2 = Hin[(size_t)s2 * HID + lane];
            const float v3 = Hin[(size_t)s3 * HID + lane];
            const float v4 = Hin[(size_t)s4 * HID + lane];
            const float v5 = Hin[(size_t)s5 * HID + lane];
            const float v6 = Hin[(size_t)s6 * HID + lane];
            const float v7 = Hin[(size_t)s7 * HID + lane];
            u += v0; u += v1; u += v2; u += v3;
            u += v4; u += v5; u += v6; u += v7;
        }
        for (; i < end; ++i) u += Hin[(size_t)srcs[i] * HID + lane];
        su[(w << 2) + q][lane] = u;
    }
    __syncthreads();

    const float bias = bl[lane];
    float a0 = bias, a1 = bias, a2 = bias, a3 = bias;
    #pragma unroll 1
    for (int c = 0; c < 2; ++c) {
        float wreg[32];
        #pragma unroll
        for (int k = 0; k < 32; ++k) wreg[k] = Wl[(size_t)(c * 32 + k) * HID + lane];
        #pragma unroll
        for (int kk = 0; kk < 8; ++kk) {
            const int k0 = c * 32 + kk * 4;
            const float4 r0 = *(const float4*)&su[w     ][k0];
            const float4 r1 = *(const float4*)&su[w +  4][k0];
            const float4 r2 = *(const float4*)&su[w +  8][k0];
            const float4 r3 = *(const float4*)&su[w + 12][k0];
            const float w0 = wreg[kk*4], w1 = wreg[kk*4+1], w2 = wreg[kk*4+2], w3 = wreg[kk*4+3];
            a0 += r0.x*w0 + r0.y*w1 + r0.z*w2 + r0.w*w3;
            a1 += r1.x*w0 + r1.y*w1 + r1.z*w2 + r1.w*w3;
            a2 += r2.x*w0 + r2.y*w1 + r2.z*w2 + r2.w*w3;
            a3 += r3.x*w0 + r3.y*w1 + r3.z*w2 + r3.w*w3;
        }
    }
    const size_t ob = (size_t)row0 * HID + lane;
    Hout[ob +  w       * HID] = fmaxf(a0, 0.f);
    Hout[ob + (w +  4) * HID] = fmaxf(a1, 0.f);
    Hout[ob + (w +  8) * HID] = fmaxf(a2, 0.f);
    Hout[ob + (w + 12) * HID] = fmaxf(a3, 0.f);
}

// ---------------- classifier ----------------------------------------------
__global__ __launch_bounds__(256) void k_cls(
    const float* __restrict__ Wc, const float* __restrict__ bc,
    const float* __restrict__ H, float* __restrict__ out)
{
    __shared__ float su[16][HID];
    const int t = threadIdx.x;
    const int lane = t & 63;
    const int w    = t >> 6;
    const int row0 = blockIdx.x * 16;
    const float4* usrc = (const float4*)(H + (size_t)row0 * HID);
    for (int i = t; i < 16 * HID / 4; i += 256) ((float4*)su)[i] = usrc[i];
    __syncthreads();

    if (lane >= NCLS) return;
    const float bias = bc[lane];
    float a0 = bias, a1 = bias, a2 = bias, a3 = bias;
    #pragma unroll 1
    for (int c = 0; c < 2; ++c) {
        float wreg[32];
        #pragma unroll
        for (int k = 0; k < 32; ++k) wreg[k] = Wc[(size_t)(c * 32 + k) * NCLS + lane];
        #pragma unroll
        for (int kk = 0; kk < 8; ++kk) {
            const int k0 = c * 32 + kk * 4;
            const float4 r0 = *(const float4*)&su[w     ][k0];
            const float4 r1 = *(const float4*)&su[w +  4][k0];
            const float4 r2 = *(const float4*)&su[w +  8][k0];
            const float4 r3 = *(const float4*)&su[w + 12][k0];
            const float w0 = wreg[kk*4], w1 = wreg[kk*4+1], w2 = wreg[kk*4+2], w3 = wreg[kk*4+3];
            a0 += r0.x*w0 + r0.y*w1 + r0.z*w2 + r0.w*w3;
            a1 += r1.x*w0 + r1.y*w1 + r1.z*w2 + r1.w*w3;
            a2 += r2.x*w0 + r2.y*w1 + r2.z*w2 + r2.w*w3;
            a3 += r3.x*w0 + r3.y*w1 + r3.z*w2 + r3.w*w3;
        }
    }
    const size_t base = (size_t)row0 * NCLS + lane;
    out[base +  w       * NCLS] = a0;
    out[base + (w +  4) * NCLS] = a1;
    out[base + (w +  8) * NCLS] = a2;
    out[base + (w + 12) * NCLS] = a3;
}

extern "C" void kernel_launch(void* const* d_in, const int* in_sizes, int n_in,
                              void* d_out, int out_size, void* d_ws, size_t ws_size,
                              hipStream_t stream)
{
    const float* x        = (const float*)d_in[0];
    const int*   ei       = (const int*)  d_in[1];
    const float* W_in     = (const float*)d_in[2];
    const float* b_in     = (const float*)d_in[3];
    const float* W_layers = (const float*)d_in[4];
    const float* b_layers = (const float*)d_in[5];
    const float* W_cls    = (const float*)d_in[6];
    const float* b_cls    = (const float*)d_in[7];
    float* out = (float*)d_out;

    // ws: two 25.6 MB node-feature buffers (ping-pong)
    float* H0 = (float*)d_ws;
    float* H1 = H0 + (size_t)N_NODES * HID;

    // build scratch lives in the x input buffer (51.2 MB = 12.8M ints), used
    // only AFTER k_in_gemm consumed x (stream-ordered). Harness restores
    // inputs from pristine before every launch, so clobbering is sanctioned.
    int* xb        = (int*)d_in[0];
    int* pairs     = xb;                          // 1.6M ints
    int* srcs      = xb + E_NUM;                  // 1.6M ints
    int* row_start = xb + 2 * E_NUM;              // 100001 ints
    int* hist      = xb + 2 * E_NUM + 100064;     // 782
    int* base      = hist + 1024;                 // 783
    int* cursor    = base + 1024;                 // 782

    const int gemm_blocks = N_NODES / 16;         // 6250

    k_in_gemm  <<<gemm_blocks, 256, 0, stream>>>(x, W_in, b_in, H0);

    k_zero_hist<<<4, 256, 0, stream>>>(hist);
    k_hist     <<<NTILE, 256, 0, stream>>>(ei, hist);
    k_scan     <<<1, 1024, 0, stream>>>(hist, base, cursor);
    k_part     <<<NTILE, 256, 0, stream>>>(ei, cursor, pairs);
    k_bsort    <<<NBUCK, 256, 0, stream>>>(base, pairs, srcs, row_start);

    float* Hi = H0; float* Ho = H1;
    for (int i = 0; i < 3; ++i) {
        k_gather_gemm<<<gemm_blocks, 256, 0, stream>>>(
            row_start, srcs, Hi,
            W_layers + (size_t)i * HID * HID, b_layers + (size_t)i * HID, Ho);
        float* tmp = Hi; Hi = Ho; Ho = tmp;
    }
    k_cls<<<gemm_blocks, 256, 0, stream>>>(W_cls, b_cls, Hi, out);
}

// Round 6
// 487.175 us; speedup vs baseline: 1.2611x; 1.2611x over previous
//
#include <hip/hip_runtime.h>
#include <hip/hip_bf16.h>

#define N_NODES 100000
#define E_NUM   1600000
#define IN_DIM  128
#define HID     64
#define NCLS    40
#define NBUCK   782      // ceil(N_NODES/128); bucket b owns nodes [b*128, b*128+128)
#define TILE_E  8192
#define NTILE   196      // ceil(E_NUM / TILE_E)

// ---------------- K1: H = relu(x @ W_in + b_in) ----------------------------
// sW in LDS (staged once, overlaps nothing to lose); sx rows read as
// broadcast float4 (ds_read_b128, same-address across wave = free); sW read
// lane-indexed b32 (2 lanes/bank = free).
__global__ __launch_bounds__(256) void k_in_gemm(
    const float* __restrict__ x, const float* __restrict__ W,
    const float* __restrict__ b, float* __restrict__ H)
{
    __shared__ float sW[IN_DIM * HID];   // 32 KB, [k][j]
    __shared__ float sx[16][IN_DIM];     // 8 KB
    const int t = threadIdx.x;
    const int lane = t & 63;
    const int w    = t >> 6;
    for (int i = t; i < IN_DIM * HID; i += 256) sW[i] = W[i];
    const int row0 = blockIdx.x * 16;    // N_NODES = 16 * 6250
    const float4* xsrc = (const float4*)(x + (size_t)row0 * IN_DIM);
    for (int i = t; i < 16 * IN_DIM / 4; i += 256) ((float4*)sx)[i] = xsrc[i];
    __syncthreads();

    const float bias = b[lane];
    float a0 = bias, a1 = bias, a2 = bias, a3 = bias;
    #pragma unroll
    for (int kk = 0; kk < IN_DIM / 4; ++kk) {
        const int k0 = kk * 4;
        const float w0 = sW[(k0    ) * HID + lane];
        const float w1 = sW[(k0 + 1) * HID + lane];
        const float w2 = sW[(k0 + 2) * HID + lane];
        const float w3 = sW[(k0 + 3) * HID + lane];
        const float4 r0 = *(const float4*)&sx[w     ][k0];
        const float4 r1 = *(const float4*)&sx[w +  4][k0];
        const float4 r2 = *(const float4*)&sx[w +  8][k0];
        const float4 r3 = *(const float4*)&sx[w + 12][k0];
        a0 += r0.x*w0 + r0.y*w1 + r0.z*w2 + r0.w*w3;
        a1 += r1.x*w0 + r1.y*w1 + r1.z*w2 + r1.w*w3;
        a2 += r2.x*w0 + r2.y*w1 + r2.z*w2 + r2.w*w3;
        a3 += r3.x*w0 + r3.y*w1 + r3.z*w2 + r3.w*w3;
    }
    const size_t base = (size_t)row0 * HID + lane;
    H[base +  w       * HID] = fmaxf(a0, 0.f);
    H[base + (w +  4) * HID] = fmaxf(a1, 0.f);
    H[base + (w +  8) * HID] = fmaxf(a2, 0.f);
    H[base + (w + 12) * HID] = fmaxf(a3, 0.f);
}

// ---------------- bucket partition + in-bucket CSR build -------------------
__global__ void k_zero_hist(int* __restrict__ h) {
    int i = blockIdx.x * 256 + threadIdx.x;
    if (i < NBUCK) h[i] = 0;
}

__global__ __launch_bounds__(256) void k_hist(
    const int* __restrict__ ei, int* __restrict__ hist)
{
    __shared__ int lh[NBUCK];
    const int t = threadIdx.x;
    for (int i = t; i < NBUCK; i += 256) lh[i] = 0;
    __syncthreads();
    const int e0 = blockIdx.x * TILE_E;
    for (int k = 0; k < TILE_E; k += 256) {
        int e = e0 + k + t;
        if (e < E_NUM) atomicAdd(&lh[ei[E_NUM + e] >> 7], 1);
    }
    __syncthreads();
    for (int i = t; i < NBUCK; i += 256) if (lh[i]) atomicAdd(&hist[i], lh[i]);
}

__global__ __launch_bounds__(1024) void k_scan(
    const int* __restrict__ hist, int* __restrict__ base, int* __restrict__ cursor)
{
    __shared__ int s[1024];
    const int t = threadIdx.x;
    const int v = (t < NBUCK) ? hist[t] : 0;
    s[t] = v; __syncthreads();
    for (int off = 1; off < 1024; off <<= 1) {
        int a = (t >= off) ? s[t - off] : 0;
        __syncthreads(); s[t] += a; __syncthreads();
    }
    if (t < NBUCK) { int ex = s[t] - v; base[t] = ex; cursor[t] = ex; }
    if (t == NBUCK) base[t] = E_NUM;
}

// tile-private chunk reservation -> block-exclusive contiguous writes
__global__ __launch_bounds__(256) void k_part(
    const int* __restrict__ ei, int* __restrict__ cursor, int* __restrict__ pairs)
{
    __shared__ int lh[NBUCK];
    __shared__ int lbase[NBUCK];
    __shared__ int lcnt[NBUCK];
    const int t = threadIdx.x;
    for (int i = t; i < NBUCK; i += 256) { lh[i] = 0; lcnt[i] = 0; }
    __syncthreads();
    const int e0 = blockIdx.x * TILE_E;
    for (int k = 0; k < TILE_E; k += 256) {
        int e = e0 + k + t;
        if (e < E_NUM) atomicAdd(&lh[ei[E_NUM + e] >> 7], 1);
    }
    __syncthreads();
    for (int i = t; i < NBUCK; i += 256)
        lbase[i] = lh[i] ? atomicAdd(&cursor[i], lh[i]) : 0;
    __syncthreads();
    for (int k = 0; k < TILE_E; k += 256) {
        int e = e0 + k + t;
        if (e < E_NUM) {
            int src = ei[e];
            int dst = ei[E_NUM + e];
            int b   = dst >> 7;
            int r   = atomicAdd(&lcnt[b], 1);
            pairs[lbase[b] + r] = (src << 7) | (dst & 127);  // src < 2^17, fits
        }
    }
}

// one block per bucket: exact per-node CSR, writes stay in block-owned region
__global__ __launch_bounds__(256) void k_bsort(
    const int* __restrict__ base, const int* __restrict__ pairs,
    int* __restrict__ srcs, int* __restrict__ row_start)
{
    __shared__ int cnt[128];
    __shared__ int sc[128];
    __shared__ int cur[128];
    const int t = threadIdx.x;
    const int b = blockIdx.x;
    const int beg = base[b], end = base[b + 1];
    if (t < 128) cnt[t] = 0;
    __syncthreads();
    for (int i = beg + t; i < end; i += 256)
        atomicAdd(&cnt[pairs[i] & 127], 1);
    __syncthreads();
    if (t < 128) sc[t] = cnt[t];
    __syncthreads();
    for (int off = 1; off < 128; off <<= 1) {
        int a = (t < 128 && t >= off) ? sc[t - off] : 0;
        __syncthreads();
        if (t < 128) sc[t] += a;
        __syncthreads();
    }
    const int node0 = b << 7;
    if (t < 128) {
        int ex = sc[t] - cnt[t];      // exclusive prefix within bucket
        cur[t] = ex;
        if (node0 + t < N_NODES) row_start[node0 + t] = beg + ex;
    }
    if (b == 0 && t == 0) row_start[N_NODES] = E_NUM;
    __syncthreads();
    for (int i = beg + t; i < end; i += 256) {
        int p = pairs[i];
        int r = atomicAdd(&cur[p & 127], 1);
        srcs[beg + r] = p >> 7;
    }
}

// ------- fused: U = H[n] + sum H[src]  then  Hout = relu(U @ W + b) --------
// r4 structure (sW staged to LDS before gather, 20 KB LDS, low VGPR) with the
// quad-k tail: per 4 k's, 4 conflict-free b32 sW reads + 4 broadcast b128 su
// reads -> 128 DS instrs/thread instead of 320.
__global__ __launch_bounds__(256) void k_gather_gemm(
    const int* __restrict__ row_start, const int* __restrict__ srcs,
    const float* __restrict__ Hin, const float* __restrict__ Wl,
    const float* __restrict__ bl, float* __restrict__ Hout)
{
    __shared__ float sW[HID * HID];   // 16 KB, [k][j]
    __shared__ float su[16][HID];     // 4 KB
    const int t = threadIdx.x;
    for (int i = t; i < HID * HID; i += 256) sW[i] = Wl[i];
    const int lane = t & 63;
    const int w    = t >> 6;
    const int row0 = blockIdx.x * 16;

    for (int q = 0; q < 4; ++q) {
        const int n = row0 + (w << 2) + q;
        const int beg = row_start[n];
        const int end = row_start[n + 1];
        float u = Hin[(size_t)n * HID + lane];
        int i = beg;
        for (; i + 7 < end; i += 8) {
            const int s0 = srcs[i    ], s1 = srcs[i + 1], s2 = srcs[i + 2], s3 = srcs[i + 3];
            const int s4 = srcs[i + 4], s5 = srcs[i + 5], s6 = srcs[i + 6], s7 = srcs[i + 7];
            const float v0 = Hin[(size_t)s0 * HID + lane];
            const float v1 = Hin[(size_t)s1 * HID + lane];
            const float v2 = Hin[(size_t)s2 * HID + lane];
            const float v3 = Hin[(size_t)s3 * HID + lane];
            const float v4 = Hin[(size_t)s4 * HID + lane];
            const float v5 = Hin[(size_t)s5 * HID + lane];
            const float v6 = Hin[(size_t)s6 * HID + lane];
            const float v7 = Hin[(size_t)s7 * HID + lane];
            u += v0; u += v1; u += v2; u += v3;
            u += v4; u += v5; u += v6; u += v7;
        }
        for (; i < end; ++i) u += Hin[(size_t)srcs[i] * HID + lane];
        su[(w << 2) + q][lane] = u;
    }
    __syncthreads();

    const float bias = bl[lane];
    float a0 = bias, a1 = bias, a2 = bias, a3 = bias;
    #pragma unroll
    for (int kk = 0; kk < HID / 4; ++kk) {
        const int k0 = kk * 4;
        const float w0 = sW[(k0    ) * HID + lane];
        const float w1 = sW[(k0 + 1) * HID + lane];
        const float w2 = sW[(k0 + 2) * HID + lane];
        const float w3 = sW[(k0 + 3) * HID + lane];
        const float4 r0 = *(const float4*)&su[w     ][k0];
        const float4 r1 = *(const float4*)&su[w +  4][k0];
        const float4 r2 = *(const float4*)&su[w +  8][k0];
        const float4 r3 = *(const float4*)&su[w + 12][k0];
        a0 += r0.x*w0 + r0.y*w1 + r0.z*w2 + r0.w*w3;
        a1 += r1.x*w0 + r1.y*w1 + r1.z*w2 + r1.w*w3;
        a2 += r2.x*w0 + r2.y*w1 + r2.z*w2 + r2.w*w3;
        a3 += r3.x*w0 + r3.y*w1 + r3.z*w2 + r3.w*w3;
    }
    const size_t ob = (size_t)row0 * HID + lane;
    Hout[ob +  w       * HID] = fmaxf(a0, 0.f);
    Hout[ob + (w +  4) * HID] = fmaxf(a1, 0.f);
    Hout[ob + (w +  8) * HID] = fmaxf(a2, 0.f);
    Hout[ob + (w + 12) * HID] = fmaxf(a3, 0.f);
}

// ---------------- classifier ----------------------------------------------
__global__ __launch_bounds__(256) void k_cls(
    const float* __restrict__ Wc, const float* __restrict__ bc,
    const float* __restrict__ H, float* __restrict__ out)
{
    __shared__ float sW[HID * NCLS];  // 10 KB, [k][j]
    __shared__ float su[16][HID];
    const int t = threadIdx.x;
    const int lane = t & 63;
    const int w    = t >> 6;
    for (int i = t; i < HID * NCLS; i += 256) sW[i] = Wc[i];
    const int row0 = blockIdx.x * 16;
    const float4* usrc = (const float4*)(H + (size_t)row0 * HID);
    for (int i = t; i < 16 * HID / 4; i += 256) ((float4*)su)[i] = usrc[i];
    __syncthreads();

    if (lane >= NCLS) return;
    const float bias = bc[lane];
    float a0 = bias, a1 = bias, a2 = bias, a3 = bias;
    #pragma unroll
    for (int kk = 0; kk < HID / 4; ++kk) {
        const int k0 = kk * 4;
        const float w0 = sW[(k0    ) * NCLS + lane];
        const float w1 = sW[(k0 + 1) * NCLS + lane];
        const float w2 = sW[(k0 + 2) * NCLS + lane];
        const float w3 = sW[(k0 + 3) * NCLS + lane];
        const float4 r0 = *(const float4*)&su[w     ][k0];
        const float4 r1 = *(const float4*)&su[w +  4][k0];
        const float4 r2 = *(const float4*)&su[w +  8][k0];
        const float4 r3 = *(const float4*)&su[w + 12][k0];
        a0 += r0.x*w0 + r0.y*w1 + r0.z*w2 + r0.w*w3;
        a1 += r1.x*w0 + r1.y*w1 + r1.z*w2 + r1.w*w3;
        a2 += r2.x*w0 + r2.y*w1 + r2.z*w2 + r2.w*w3;
        a3 += r3.x*w0 + r3.y*w1 + r3.z*w2 + r3.w*w3;
    }
    const size_t base = (size_t)row0 * NCLS + lane;
    out[base +  w       * NCLS] = a0;
    out[base + (w +  4) * NCLS] = a1;
    out[base + (w +  8) * NCLS] = a2;
    out[base + (w + 12) * NCLS] = a3;
}

extern "C" void kernel_launch(void* const* d_in, const int* in_sizes, int n_in,
                              void* d_out, int out_size, void* d_ws, size_t ws_size,
                              hipStream_t stream)
{
    const float* x        = (const float*)d_in[0];
    const int*   ei       = (const int*)  d_in[1];
    const float* W_in     = (const float*)d_in[2];
    const float* b_in     = (const float*)d_in[3];
    const float* W_layers = (const float*)d_in[4];
    const float* b_layers = (const float*)d_in[5];
    const float* W_cls    = (const float*)d_in[6];
    const float* b_cls    = (const float*)d_in[7];
    float* out = (float*)d_out;

    // ws: two 25.6 MB node-feature buffers (ping-pong)
    float* H0 = (float*)d_ws;
    float* H1 = H0 + (size_t)N_NODES * HID;

    // build scratch lives in the x input buffer (51.2 MB = 12.8M ints), used
    // only AFTER k_in_gemm consumed x (stream-ordered). Harness restores
    // inputs from pristine before every launch, so clobbering is sanctioned.
    int* xb        = (int*)d_in[0];
    int* pairs     = xb;                          // 1.6M ints
    int* srcs      = xb + E_NUM;                  // 1.6M ints
    int* row_start = xb + 2 * E_NUM;              // 100001 ints
    int* hist      = xb + 2 * E_NUM + 100064;     // 782
    int* base      = hist + 1024;                 // 783
    int* cursor    = base + 1024;                 // 782

    const int gemm_blocks = N_NODES / 16;         // 6250

    k_in_gemm  <<<gemm_blocks, 256, 0, stream>>>(x, W_in, b_in, H0);

    k_zero_hist<<<4, 256, 0, stream>>>(hist);
    k_hist     <<<NTILE, 256, 0, stream>>>(ei, hist);
    k_scan     <<<1, 1024, 0, stream>>>(hist, base, cursor);
    k_part     <<<NTILE, 256, 0, stream>>>(ei, cursor, pairs);
    k_bsort    <<<NBUCK, 256, 0, stream>>>(base, pairs, srcs, row_start);

    float* Hi = H0; float* Ho = H1;
    for (int i = 0; i < 3; ++i) {
        k_gather_gemm<<<gemm_blocks, 256, 0, stream>>>(
            row_start, srcs, Hi,
            W_layers + (size_t)i * HID * HID, b_layers + (size_t)i * HID, Ho);
        float* tmp = Hi; Hi = Ho; Ho = tmp;
    }
    k_cls<<<gemm_blocks, 256, 0, stream>>>(W_cls, b_cls, Hi, out);
}